// Round 6
// baseline (156.414 us; speedup 1.0000x reference)
//
#include <hip/hip_runtime.h>
#include <hip/hip_bf16.h>
#include <math.h>

#define SEQ    1024
#define DMODEL 512
#define OUT0   2097152      // 4*1024*512 (output 0 size)
#define SP_EPS 1e-7f
#define INV_T  0.125f       // 1/sqrt(64)

typedef __attribute__((ext_vector_type(8))) short bf16x8;
typedef __attribute__((ext_vector_type(4))) float f32x4;

// ---------------- bf16 split helpers (RN-to-nearest-even) ------------------
__device__ __forceinline__ unsigned short f2bf(float f) {
  unsigned int b = __float_as_uint(f);
  return (unsigned short)((b + 0x7fffu + ((b >> 16) & 1u)) >> 16);
}
__device__ __forceinline__ float bf2f(unsigned short u) {
  return __uint_as_float(((unsigned int)u) << 16);
}

__device__ __forceinline__ float wred_max(float v) {
#pragma unroll
  for (int o = 32; o > 0; o >>= 1) v = fmaxf(v, __shfl_xor(v, o));
  return v;
}
__device__ __forceinline__ float wred_sum(float v) {
#pragma unroll
  for (int o = 32; o > 0; o >>= 1) v += __shfl_xor(v, o);
  return v;
}

// ---------------- kernel 0: split-convert 2 or 3 weight matrices -----------
// dst layout per z: hi @ z*2^19, lo @ z*2^19 + 2^18 (each 256K elems)
__global__ __launch_bounds__(256) void convW_kernel(
    const float* __restrict__ w0, const float* __restrict__ w1,
    const float* __restrict__ w2, unsigned short* __restrict__ dst)
{
  const int z = blockIdx.z;
  const float* src = (z == 0) ? w0 : (z == 1) ? w1 : w2;
  unsigned short* hi = dst + (size_t)z * (1u << 19);
  unsigned short* lo = hi + (1u << 18);
  const int i = (blockIdx.x * 256 + threadIdx.x) * 4;
  const float4 x = *(const float4*)(src + i);
  ushort4 h, l;
  h.x = f2bf(x.x); l.x = f2bf(x.x - bf2f(h.x));
  h.y = f2bf(x.y); l.y = f2bf(x.y - bf2f(h.y));
  h.z = f2bf(x.z); l.z = f2bf(x.z - bf2f(h.z));
  h.w = f2bf(x.w); l.w = f2bf(x.w - bf2f(h.w));
  *(ushort4*)(hi + i) = h;
  *(ushort4*)(lo + i) = l;
}

// ---------------- kernel 1: QKV projection via split-bf16 MFMA -------------
// BM=64, BN=128, BK=64; 4 waves (2x2). A (q/k/v f32) is split in-register
// during staging; W pre-split. q,k out as hi/lo bf16; v out f32.
__global__ __launch_bounds__(256) void qkv_mfma_kernel(
    const float* __restrict__ q, const float* __restrict__ k, const float* __restrict__ v,
    const unsigned short* __restrict__ Wsplit,
    const float* __restrict__ bq, const float* __restrict__ bk, const float* __restrict__ bv,
    unsigned short* __restrict__ qhh, unsigned short* __restrict__ qhl,
    unsigned short* __restrict__ khh, unsigned short* __restrict__ khl,
    float* __restrict__ vh)
{
  __shared__ short Ash[64 * 64], Asl[64 * 64];
  __shared__ short Bsh[128 * 64], Bsl[128 * 64];
  const int z = blockIdx.z;
  const float* A = (z == 0) ? q : (z == 1) ? k : v;
  const unsigned short* Wh = Wsplit + (size_t)z * (1u << 19);
  const unsigned short* Wl = Wh + (1u << 18);
  const float* bias = (z == 0) ? bq : (z == 1) ? bk : bv;
  const int r0 = blockIdx.x * 64, n0 = blockIdx.y * 128;
  const int tid = threadIdx.x, lane = tid & 63, w = tid >> 6;
  const int wr = w >> 1, wc = w & 1;
  const int l15 = lane & 15, l4 = lane >> 4;

  f32x4 acc[2][4];
#pragma unroll
  for (int a = 0; a < 2; ++a)
#pragma unroll
    for (int b = 0; b < 4; ++b) acc[a][b] = (f32x4){0.f, 0.f, 0.f, 0.f};

  for (int kt = 0; kt < 8; ++kt) {
    __syncthreads();
#pragma unroll
    for (int p = 0; p < 2; ++p) {
      const int c = tid + p * 256, row = c >> 3, k8 = (c & 7) * 8;
      const float4 x0 = *(const float4*)(A + (size_t)(r0 + row) * 512 + kt * 64 + k8);
      const float4 x1 = *(const float4*)(A + (size_t)(r0 + row) * 512 + kt * 64 + k8 + 4);
      bf16x8 hv, lv;
      const float xs[8] = {x0.x, x0.y, x0.z, x0.w, x1.x, x1.y, x1.z, x1.w};
#pragma unroll
      for (int j = 0; j < 8; ++j) {
        const unsigned short h = f2bf(xs[j]);
        hv[j] = (short)h; lv[j] = (short)f2bf(xs[j] - bf2f(h));
      }
      const int si = row * 64 + (k8 ^ ((row & 7) << 3));
      *(bf16x8*)&Ash[si] = hv; *(bf16x8*)&Asl[si] = lv;
    }
#pragma unroll
    for (int p = 0; p < 4; ++p) {
      const int c = tid + p * 256, row = c >> 3, k8 = (c & 7) * 8;
      const size_t go = (size_t)(n0 + row) * 512 + kt * 64 + k8;
      const int si = row * 64 + (k8 ^ ((row & 7) << 3));
      *(bf16x8*)&Bsh[si] = *(const bf16x8*)(Wh + go);
      *(bf16x8*)&Bsl[si] = *(const bf16x8*)(Wl + go);
    }
    __syncthreads();
#pragma unroll
    for (int kf = 0; kf < 2; ++kf) {
      const int kb = kf * 32 + l4 * 8;
      bf16x8 ah[2], al2[2];
#pragma unroll
      for (int rb = 0; rb < 2; ++rb) {
        const int ar = wr * 32 + rb * 16 + l15;
        const int si = ar * 64 + (kb ^ ((ar & 7) << 3));
        ah[rb] = *(bf16x8*)&Ash[si]; al2[rb] = *(bf16x8*)&Asl[si];
      }
#pragma unroll
      for (int cb = 0; cb < 4; ++cb) {
        const int br = wc * 64 + cb * 16 + l15;
        const int si = br * 64 + (kb ^ ((br & 7) << 3));
        const bf16x8 bh = *(bf16x8*)&Bsh[si];
        const bf16x8 bl = *(bf16x8*)&Bsl[si];
#pragma unroll
        for (int rb = 0; rb < 2; ++rb) {
          acc[rb][cb] = __builtin_amdgcn_mfma_f32_16x16x32_bf16(al2[rb], bh, acc[rb][cb], 0, 0, 0);
          acc[rb][cb] = __builtin_amdgcn_mfma_f32_16x16x32_bf16(ah[rb], bl, acc[rb][cb], 0, 0, 0);
          acc[rb][cb] = __builtin_amdgcn_mfma_f32_16x16x32_bf16(ah[rb], bh, acc[rb][cb], 0, 0, 0);
        }
      }
    }
  }
  unsigned short* H = (z == 0) ? qhh : khh;
  unsigned short* L = (z == 0) ? qhl : khl;
#pragma unroll
  for (int cb = 0; cb < 4; ++cb) {
    const int col = n0 + wc * 64 + cb * 16 + l15;
    const float bia = bias[col];
    const int h = col >> 6, d = col & 63;
#pragma unroll
    for (int rb = 0; rb < 2; ++rb)
#pragma unroll
      for (int ri = 0; ri < 4; ++ri) {
        const int row = r0 + wr * 32 + rb * 16 + l4 * 4 + ri;
        const int b = row >> 10, ll = row & 1023;
        const size_t idx = ((size_t)(h * 4 + b) << 16) + (ll << 6) + d;
        const float val = acc[rb][cb][ri] + bia;
        if (z == 2) {
          vh[idx] = val;
        } else {
          const unsigned short hv = f2bf(val);
          H[idx] = hv;
          L[idx] = f2bf(val - bf2f(hv));
        }
      }
  }
}

// ---------------- kernel 2: FUSED scores + softmax + top6 + sparse PV ------
// Per block: 16 rows x 1024 cols of one bh. 8 waves.
// Phase A: wave w computes cols [w*128, w*128+128) via split-bf16 MFMA with
// fragments loaded directly from global qh/kh splits (L2-resident) into a
// 16x1028 f32 LDS tile. Phase B: 2 rows/wave: branch-free top-6, weight
// write (final attn output), sparse PV, out_full hi/lo split write.
__global__ __launch_bounds__(512, 4) void scores_sparse_fused_kernel(
    const unsigned short* __restrict__ qhh, const unsigned short* __restrict__ qhl,
    const unsigned short* __restrict__ khh, const unsigned short* __restrict__ khl,
    const float* __restrict__ vh, float* __restrict__ attn,
    unsigned short* __restrict__ ofhi, unsigned short* __restrict__ oflo)
{
  __shared__ float S[16 * 1028];
  __shared__ float s_w[8][8];
  __shared__ int   s_i[8][8];
  const int bh = blockIdx.y;
  const int r0g = blockIdx.x * 16;
  const int tid = threadIdx.x, lane = tid & 63, w = tid >> 6;
  const int l15 = lane & 15, l4 = lane >> 4;
  const size_t base = (size_t)bh << 16;

  // ---- Phase A: scores ----
  bf16x8 qh8[2], ql8[2];
#pragma unroll
  for (int kf = 0; kf < 2; ++kf) {
    const size_t qa = base + (size_t)(r0g + l15) * 64 + kf * 32 + l4 * 8;
    qh8[kf] = *(const bf16x8*)(qhh + qa);
    ql8[kf] = *(const bf16x8*)(qhl + qa);
  }
#pragma unroll
  for (int cb = 0; cb < 8; ++cb) {
    f32x4 acc = (f32x4){0.f, 0.f, 0.f, 0.f};
    const size_t kr = base + (size_t)(w * 128 + cb * 16 + l15) * 64;
#pragma unroll
    for (int kf = 0; kf < 2; ++kf) {
      const bf16x8 kh8 = *(const bf16x8*)(khh + kr + kf * 32 + l4 * 8);
      const bf16x8 kl8 = *(const bf16x8*)(khl + kr + kf * 32 + l4 * 8);
      acc = __builtin_amdgcn_mfma_f32_16x16x32_bf16(ql8[kf], kh8, acc, 0, 0, 0);
      acc = __builtin_amdgcn_mfma_f32_16x16x32_bf16(qh8[kf], kl8, acc, 0, 0, 0);
      acc = __builtin_amdgcn_mfma_f32_16x16x32_bf16(qh8[kf], kh8, acc, 0, 0, 0);
    }
    const int col = w * 128 + cb * 16 + l15;
#pragma unroll
    for (int ri = 0; ri < 4; ++ri)
      S[(l4 * 4 + ri) * 1028 + col] = acc[ri] * INV_T;
  }
  __syncthreads();

  // ---- Phase B: per-row sparse softmax ----
#pragma unroll
  for (int rr = 0; rr < 2; ++rr) {
    const int row_local = 2 * w + rr;
    const int lq = r0g + row_local;
    const float* Sr = S + row_local * 1028;

    float u[16];
    {
      const float4 a0 = *(const float4*)(Sr + lane * 4);
      const float4 a1 = *(const float4*)(Sr + 256 + lane * 4);
      const float4 a2 = *(const float4*)(Sr + 512 + lane * 4);
      const float4 a3 = *(const float4*)(Sr + 768 + lane * 4);
      u[0]=a0.x; u[1]=a0.y; u[2]=a0.z; u[3]=a0.w;
      u[4]=a1.x; u[5]=a1.y; u[6]=a1.z; u[7]=a1.w;
      u[8]=a2.x; u[9]=a2.y; u[10]=a2.z; u[11]=a2.w;
      u[12]=a3.x; u[13]=a3.y; u[14]=a3.z; u[15]=a3.w;
    }

    float m = -1e30f;
#pragma unroll
    for (int j = 0; j < 16; ++j) m = fmaxf(m, u[j]);
    m = wred_max(m);
    float Zl = 0.f;
#pragma unroll
    for (int j = 0; j < 16; ++j) { u[j] = __expf(u[j] - m); Zl += u[j]; }
    const float Z = wred_sum(Zl);

    // lane-local top-6 sorted desc (insertion network)
    float t0 = -1e30f, t1 = -1e30f, t2 = -1e30f, t3 = -1e30f, t4 = -1e30f, t5 = -1e30f;
#pragma unroll
    for (int j = 0; j < 16; ++j) {
      float v = u[j], a;
      a = fmaxf(t0, v); v = fminf(t0, v); t0 = a;
      a = fmaxf(t1, v); v = fminf(t1, v); t1 = a;
      a = fmaxf(t2, v); v = fminf(t2, v); t2 = a;
      a = fmaxf(t3, v); v = fminf(t3, v); t3 = a;
      a = fmaxf(t4, v); v = fminf(t4, v); t4 = a;
      t5 = fmaxf(t5, v);
    }
    // butterfly merge of sorted-6 lists
#pragma unroll
    for (int off = 1; off < 64; off <<= 1) {
      const float b0 = __shfl_xor(t0, off), b1 = __shfl_xor(t1, off),
                  b2 = __shfl_xor(t2, off), b3 = __shfl_xor(t3, off),
                  b4 = __shfl_xor(t4, off), b5 = __shfl_xor(t5, off);
      float m0 = fmaxf(t0, b5), m1 = fmaxf(t1, b4), m2 = fmaxf(t2, b3),
            m3 = fmaxf(t3, b2), m4 = fmaxf(t4, b1), m5 = fmaxf(t5, b0);
      float a;
      a = fmaxf(m0, m3); m3 = fminf(m0, m3); m0 = a;
      a = fmaxf(m1, m4); m4 = fminf(m1, m4); m1 = a;
      a = fmaxf(m2, m5); m5 = fminf(m2, m5); m2 = a;
      a = fmaxf(m0, m1); m1 = fminf(m0, m1); m0 = a;
      a = fmaxf(m0, m2); m2 = fminf(m0, m2); m0 = a;
      a = fmaxf(m1, m2); m2 = fminf(m1, m2); m1 = a;
      a = fmaxf(m3, m4); m4 = fminf(m3, m4); m3 = a;
      a = fmaxf(m3, m5); m5 = fminf(m3, m5); m3 = a;
      a = fmaxf(m4, m5); m5 = fminf(m4, m5); m4 = a;
      t0 = m0; t1 = m1; t2 = m2; t3 = m3; t4 = m4; t5 = m5;
    }

    const float du = t5 + SP_EPS * Z;
    float wv16[16], Sl = 0.f;
#pragma unroll
    for (int j = 0; j < 16; ++j) { wv16[j] = fmaxf(u[j] - du, 0.f); Sl += wv16[j]; }
    const float Ssum = wred_sum(Sl);
    const float inv = 1.0f / (Ssum + SP_EPS * Z);
#pragma unroll
    for (int j = 0; j < 16; ++j) wv16[j] *= inv;

    float* rp = attn + (((size_t)(bh << 10) + lq) << 10);
    *(float4*)(rp +       lane * 4) = make_float4(wv16[0],  wv16[1],  wv16[2],  wv16[3]);
    *(float4*)(rp + 256 + lane * 4) = make_float4(wv16[4],  wv16[5],  wv16[6],  wv16[7]);
    *(float4*)(rp + 512 + lane * 4) = make_float4(wv16[8],  wv16[9],  wv16[10], wv16[11]);
    *(float4*)(rp + 768 + lane * 4) = make_float4(wv16[12], wv16[13], wv16[14], wv16[15]);

    int nb = 0;
#pragma unroll
    for (int j = 0; j < 16; ++j) {
      const unsigned long long b = __ballot(wv16[j] > 0.f);
      if (wv16[j] > 0.f) {
        const int pos = nb + __popcll(b & ((1ull << lane) - 1ull));
        if (pos < 8) { s_w[w][pos] = wv16[j]; s_i[w][pos] = (j >> 2) * 256 + lane * 4 + (j & 3); }
      }
      nb += __popcll(b);
    }
    if (nb > 8) nb = 8;

    float acc = 0.f;
    const float* vb = vh + base;
    for (int t = 0; t < nb; ++t)
      acc = fmaf(s_w[w][t], vb[((size_t)s_i[w][t] << 6) + lane], acc);
    const int b_ = bh & 3, h = bh >> 2;
    const int idx = (((b_ << 10) | lq) << 9) + (h << 6) + lane;
    const unsigned short hv = f2bf(acc);
    ofhi[idx] = hv;
    oflo[idx] = f2bf(acc - bf2f(hv));
  }
}

// ---------------- kernel 3: fc+gate via split-bf16 MFMA + fused epilogue ---
// A pre-split (ofhi/oflo); Wfc/Wg pre-split (FG).
__global__ __launch_bounds__(256) void out_proj_mfma_kernel(
    const unsigned short* __restrict__ ofhi, const unsigned short* __restrict__ oflo,
    const unsigned short* __restrict__ FG,
    const float* __restrict__ bfc, const float* __restrict__ bg,
    float* __restrict__ out)
{
  __shared__ short Ash[64 * 64], Asl[64 * 64];
  __shared__ short Bfh[128 * 64], Bfl[128 * 64];
  __shared__ short Bgh[128 * 64], Bgl[128 * 64];
  const unsigned short* Wfh = FG;
  const unsigned short* Wfl = FG + (1u << 18);
  const unsigned short* Wgh = FG + (1u << 19);
  const unsigned short* Wgl = FG + (1u << 19) + (1u << 18);
  const int r0 = blockIdx.x * 64, n0 = blockIdx.y * 128;
  const int tid = threadIdx.x, lane = tid & 63, w = tid >> 6;
  const int wr = w >> 1, wc = w & 1;
  const int l15 = lane & 15, l4 = lane >> 4;

  f32x4 accf[2][4], accg[2][4];
#pragma unroll
  for (int a = 0; a < 2; ++a)
#pragma unroll
    for (int b = 0; b < 4; ++b) {
      accf[a][b] = (f32x4){0.f, 0.f, 0.f, 0.f};
      accg[a][b] = (f32x4){0.f, 0.f, 0.f, 0.f};
    }

  for (int kt = 0; kt < 8; ++kt) {
    __syncthreads();
#pragma unroll
    for (int p = 0; p < 2; ++p) {
      const int c = tid + p * 256, row = c >> 3, k8 = (c & 7) * 8;
      const size_t go = (size_t)(r0 + row) * 512 + kt * 64 + k8;
      const int si = row * 64 + (k8 ^ ((row & 7) << 3));
      *(bf16x8*)&Ash[si] = *(const bf16x8*)(ofhi + go);
      *(bf16x8*)&Asl[si] = *(const bf16x8*)(oflo + go);
    }
#pragma unroll
    for (int p = 0; p < 4; ++p) {
      const int c = tid + p * 256, row = c >> 3, k8 = (c & 7) * 8;
      const int si = row * 64 + (k8 ^ ((row & 7) << 3));
      const size_t go = (size_t)(n0 + row) * 512 + kt * 64 + k8;
      *(bf16x8*)&Bfh[si] = *(const bf16x8*)(Wfh + go);
      *(bf16x8*)&Bfl[si] = *(const bf16x8*)(Wfl + go);
      *(bf16x8*)&Bgh[si] = *(const bf16x8*)(Wgh + go);
      *(bf16x8*)&Bgl[si] = *(const bf16x8*)(Wgl + go);
    }
    __syncthreads();
#pragma unroll
    for (int kf = 0; kf < 2; ++kf) {
      const int kb = kf * 32 + l4 * 8;
      bf16x8 ah[2], al2[2];
#pragma unroll
      for (int rb = 0; rb < 2; ++rb) {
        const int ar = wr * 32 + rb * 16 + l15;
        const int si = ar * 64 + (kb ^ ((ar & 7) << 3));
        ah[rb] = *(bf16x8*)&Ash[si]; al2[rb] = *(bf16x8*)&Asl[si];
      }
#pragma unroll
      for (int cb = 0; cb < 4; ++cb) {
        const int br = wc * 64 + cb * 16 + l15;
        const int si = br * 64 + (kb ^ ((br & 7) << 3));
        const bf16x8 fh = *(bf16x8*)&Bfh[si];
        const bf16x8 fl = *(bf16x8*)&Bfl[si];
        const bf16x8 gh = *(bf16x8*)&Bgh[si];
        const bf16x8 gl = *(bf16x8*)&Bgl[si];
#pragma unroll
        for (int rb = 0; rb < 2; ++rb) {
          accf[rb][cb] = __builtin_amdgcn_mfma_f32_16x16x32_bf16(al2[rb], fh, accf[rb][cb], 0, 0, 0);
          accf[rb][cb] = __builtin_amdgcn_mfma_f32_16x16x32_bf16(ah[rb], fl, accf[rb][cb], 0, 0, 0);
          accf[rb][cb] = __builtin_amdgcn_mfma_f32_16x16x32_bf16(ah[rb], fh, accf[rb][cb], 0, 0, 0);
          accg[rb][cb] = __builtin_amdgcn_mfma_f32_16x16x32_bf16(al2[rb], gh, accg[rb][cb], 0, 0, 0);
          accg[rb][cb] = __builtin_amdgcn_mfma_f32_16x16x32_bf16(ah[rb], gl, accg[rb][cb], 0, 0, 0);
          accg[rb][cb] = __builtin_amdgcn_mfma_f32_16x16x32_bf16(ah[rb], gh, accg[rb][cb], 0, 0, 0);
        }
      }
    }
  }
#pragma unroll
  for (int cb = 0; cb < 4; ++cb) {
    const int col = n0 + wc * 64 + cb * 16 + l15;
    const float bf4 = bfc[col];
    const float bg4 = bg[col];
#pragma unroll
    for (int rb = 0; rb < 2; ++rb)
#pragma unroll
      for (int ri = 0; ri < 4; ++ri) {
        const int row = r0 + wr * 32 + rb * 16 + l4 * 4 + ri;
        const float f = accf[rb][cb][ri] + bf4;
        const float g = accg[rb][cb][ri] + bg4;
        out[(size_t)row * 512 + col] = tanhf(f) / (1.f + __expf(-g));
      }
  }
}

extern "C" void kernel_launch(void* const* d_in, const int* in_sizes, int n_in,
                              void* d_out, int out_size, void* d_ws, size_t ws_size,
                              hipStream_t stream) {
  const float* q   = (const float*)d_in[0];
  const float* k   = (const float*)d_in[1];
  const float* v   = (const float*)d_in[2];
  const float* Wq  = (const float*)d_in[3];
  const float* bq  = (const float*)d_in[4];
  const float* Wk  = (const float*)d_in[5];
  const float* bk  = (const float*)d_in[6];
  const float* Wv  = (const float*)d_in[7];
  const float* bv  = (const float*)d_in[8];
  const float* Wfc = (const float*)d_in[9];
  const float* bfc = (const float*)d_in[10];
  const float* Wg  = (const float*)d_in[11];
  const float* bg  = (const float*)d_in[12];

  float* out  = (float*)d_out;
  float* attn = out + OUT0;                 // (32,1024,1024) final output 1

  // qh splits live in the out0 region (8MB, dead until out_proj rewrites it)
  unsigned short* qhh = (unsigned short*)d_out;
  unsigned short* qhl = qhh + (1u << 21);

  // ws layout (24 MB total):
  //  [0,8MB)   khh/khl          (dead after fused)  -> reused for Wfc/Wg splits
  //  [8,16MB)  vh f32
  //  [16,24MB) Wq/Wk/Wv splits  (dead after qkv)    -> reused for ofhi/oflo
  char* wsb = (char*)d_ws;
  unsigned short* khh   = (unsigned short*)wsb;
  unsigned short* khl   = (unsigned short*)(wsb + (4u << 20));
  float*          vh    = (float*)(wsb + (8u << 20));
  unsigned short* Wqkv  = (unsigned short*)(wsb + (16u << 20)); // 6MB of 8
  unsigned short* ofhi  = (unsigned short*)(wsb + (16u << 20));
  unsigned short* oflo  = (unsigned short*)(wsb + (20u << 20));
  unsigned short* FG    = (unsigned short*)wsb;                  // 4MB of 8

  convW_kernel<<<dim3(256, 1, 3), 256, 0, stream>>>(Wq, Wk, Wv, Wqkv);
  qkv_mfma_kernel<<<dim3(64, 4, 3), 256, 0, stream>>>(q, k, v, Wqkv, bq, bk, bv,
                                                      qhh, qhl, khh, khl, vh);
  scores_sparse_fused_kernel<<<dim3(64, 32), 512, 0, stream>>>(qhh, qhl, khh, khl,
                                                               vh, attn, ofhi, oflo);
  convW_kernel<<<dim3(256, 1, 2), 256, 0, stream>>>(Wfc, Wg, Wg, FG);
  out_proj_mfma_kernel<<<dim3(64, 4), 256, 0, stream>>>(ofhi, oflo, FG, bfc, bg, out);
}